// Round 1
// baseline (311.346 us; speedup 1.0000x reference)
//
#include <hip/hip_runtime.h>
#include <hip/hip_cooperative_groups.h>
#include <math.h>

// BinaryTreeLSTM on MI355X — R4.
// vs R3 (293us):
//  (1) Cooperative fused tail: levels B=128..1 (8 levels) in ONE kernel,
//      16 blocks x 256thr, grid.sync() between levels. Each block stages its
//      grp's 80KB Wcf slice in LDS ONCE, reused across all 8 levels.
//      Removes 7 launches + 7x full weight re-reads.
//  (2) RT=2 (two row-tiles per wave sharing B-frags) for leaf and B=4096
//      compose: 112B loads per 10 MFMA instead of 96B per 5.
// Dispatches: prep, leaf, compose x5 (4096..256), tail = 8 (was 15).

#define MEM 256

typedef __attribute__((ext_vector_type(8))) short bf16x8;
typedef __attribute__((ext_vector_type(4))) float f32x4;

namespace cg = cooperative_groups;

__device__ __forceinline__ float sigf(float x) { return 1.0f / (1.0f + __expf(-x)); }

__device__ __forceinline__ unsigned short f2b(float f) {
  unsigned int u = __float_as_uint(f);
  u = (u + 0x7FFFu + ((u >> 16) & 1u)) >> 16;
  return (unsigned short)u;
}

// ---- Fused one-time prep: Wcf shuffle | Wxf shuffle | embs->bf16 | bias5 ----
#define NB_WCF 2560
#define NB_WXF 960
#define NB_EB 10240
__global__ __launch_bounds__(256) void k_prep(
    const float* __restrict__ Wl, const float* __restrict__ Wr,
    const float* __restrict__ Wx, const float* __restrict__ bx,
    const float* __restrict__ embs, const float* __restrict__ emb_last,
    unsigned short* __restrict__ Wcf, unsigned short* __restrict__ Wxf,
    unsigned short* __restrict__ eb, float* __restrict__ bias5) {
  int b = blockIdx.x;
  if (b < NB_WCF) {
    int idx = b * 256 + threadIdx.x;  // 1280*512
    int f = idx >> 9, r = idx & 511;
    int lane = r >> 3, j = r & 7;
    int gate = f % 5, t = f / 5;
    int grp = t & 15, kc = t >> 4;
    int k = kc * 32 + ((lane >> 4) << 3) + j;
    int n = gate * 256 + (grp << 4) + (lane & 15);
    float v = (k < 256) ? Wl[n * 256 + k] : Wr[n * 256 + (k - 256)];
    Wcf[idx] = f2b(v);
  } else if (b < NB_WCF + NB_WXF) {
    int idx = (b - NB_WCF) * 256 + threadIdx.x;  // 480*512
    int f = idx >> 9, r = idx & 511;
    int lane = r >> 3, j = r & 7;
    int gate = f % 3, t = f / 3;
    int grp = t & 15, kc = t >> 4;
    int k = kc * 32 + ((lane >> 4) << 3) + j;
    const int gmap[3] = {0, 1, 3};
    int n = gmap[gate] * 256 + (grp << 4) + (lane & 15);
    float v = (k < 300) ? Wx[n * 300 + k] : 0.0f;
    Wxf[idx] = f2b(v);
  } else if (b < NB_WCF + NB_WXF + NB_EB) {
    int idx = (b - NB_WCF - NB_WXF) * 256 + threadIdx.x;  // 8192*320
    int row = idx / 320;
    int k = idx - row * 320;
    eb[idx] = (k < 300) ? f2b(embs[row * 300 + k]) : (unsigned short)0;
  } else {
    int g = b - (NB_WCF + NB_WXF + NB_EB);  // 0..4
    __shared__ float er[300];
    for (int k = threadIdx.x; k < 300; k += 256) er[k] = emb_last[k];
    __syncthreads();
    const int map[5] = {0, 1, 2, 2, 3};
    int wrow = map[g] * 256 + threadIdx.x;
    const float* w = Wx + wrow * 300;
    float s = bx[wrow];
    for (int k = 0; k < 300; k++) s += er[k] * w[k];
    bias5[g * 256 + threadIdx.x] = s;
  }
}

// ---- Leaf: grid(64,16); wave = 2 row tiles, grp=blockIdx.y ----
__global__ __launch_bounds__(256) void k_leaf_mfma(
    const unsigned short* __restrict__ eb, const unsigned short* __restrict__ Wxf,
    const float* __restrict__ bx, float* __restrict__ cO,
    unsigned short* __restrict__ hO) {
  int lane = threadIdx.x & 63;
  int wave = threadIdx.x >> 6;
  int grp = blockIdx.y;                     // 0..15 column group
  int tb = (blockIdx.x * 4 + wave) * 2;     // 0..510 row tile base
  int m = lane & 15, quad = lane >> 4;

  f32x4 acc[2][3];
#pragma unroll
  for (int rt = 0; rt < 2; rt++)
#pragma unroll
    for (int g = 0; g < 3; g++) acc[rt][g] = (f32x4){0.f, 0.f, 0.f, 0.f};

  const unsigned short* ar0 = eb + (tb * 16 + m) * 320 + quad * 8;
  const unsigned short* ar1 = eb + ((tb + 1) * 16 + m) * 320 + quad * 8;
#pragma unroll
  for (int kc = 0; kc < 10; kc++) {
    const unsigned short* bp = Wxf + ((kc * 16 + grp) * 3) * 512 + lane * 8;
    bf16x8 b0 = *(const bf16x8*)(bp);
    bf16x8 b1 = *(const bf16x8*)(bp + 512);
    bf16x8 b2 = *(const bf16x8*)(bp + 1024);
    bf16x8 a0 = *(const bf16x8*)(ar0 + kc * 32);
    bf16x8 a1 = *(const bf16x8*)(ar1 + kc * 32);
    acc[0][0] = __builtin_amdgcn_mfma_f32_16x16x32_bf16(a0, b0, acc[0][0], 0, 0, 0);
    acc[0][1] = __builtin_amdgcn_mfma_f32_16x16x32_bf16(a0, b1, acc[0][1], 0, 0, 0);
    acc[0][2] = __builtin_amdgcn_mfma_f32_16x16x32_bf16(a0, b2, acc[0][2], 0, 0, 0);
    acc[1][0] = __builtin_amdgcn_mfma_f32_16x16x32_bf16(a1, b0, acc[1][0], 0, 0, 0);
    acc[1][1] = __builtin_amdgcn_mfma_f32_16x16x32_bf16(a1, b1, acc[1][1], 0, 0, 0);
    acc[1][2] = __builtin_amdgcn_mfma_f32_16x16x32_bf16(a1, b2, acc[1][2], 0, 0, 0);
  }
  int col = grp * 16 + m;
  float b0 = bx[col], b1 = bx[256 + col], b3 = bx[768 + col];
#pragma unroll
  for (int rt = 0; rt < 2; rt++) {
#pragma unroll
    for (int reg = 0; reg < 4; reg++) {
      int row = (tb + rt) * 16 + quad * 4 + reg;
      float u = tanhf(acc[rt][0][reg] + b0);
      float ig = sigf(acc[rt][1][reg] + b1);
      float o = sigf(acc[rt][2][reg] + b3);
      float c = ig * u;
      cO[row * MEM + col] = c;
      hO[row * MEM + col] = f2b(o * tanhf(c));
    }
  }
}

// ---- Compose (regular levels): template RT row-tiles per wave ----
template <int RT>
__global__ __launch_bounds__(256) void k_compose_mfma(
    const unsigned short* __restrict__ hprev,  // B x 512 bf16 (view)
    const float* __restrict__ cprev,           // 2B x 256 fp32
    const unsigned short* __restrict__ Wcf, const float* __restrict__ bias5,
    float* __restrict__ cO, unsigned short* __restrict__ hO, int B) {
  int lane = threadIdx.x & 63;
  int wave = threadIdx.x >> 6;
  int grp = blockIdx.y;                       // 0..15
  int tb = (blockIdx.x * 4 + wave) * RT;      // row tile base
  if (tb * 16 >= B) return;
  int m = lane & 15, quad = lane >> 4;
  const bf16x8 zz = {0, 0, 0, 0, 0, 0, 0, 0};

  f32x4 acc[RT][5];
  const unsigned short* ar[RT];
  bool ok[RT];
#pragma unroll
  for (int rt = 0; rt < RT; rt++) {
    int ra = (tb + rt) * 16 + m;
    ok[rt] = (ra < B);
    ar[rt] = hprev + ra * 512 + quad * 8;
#pragma unroll
    for (int g = 0; g < 5; g++) acc[rt][g] = (f32x4){0.f, 0.f, 0.f, 0.f};
  }

#pragma unroll
  for (int kc = 0; kc < 16; kc++) {
    const unsigned short* bp = Wcf + ((kc * 16 + grp) * 5) * 512 + lane * 8;
    bf16x8 b0 = *(const bf16x8*)(bp);
    bf16x8 b1 = *(const bf16x8*)(bp + 512);
    bf16x8 b2 = *(const bf16x8*)(bp + 1024);
    bf16x8 b3 = *(const bf16x8*)(bp + 1536);
    bf16x8 b4 = *(const bf16x8*)(bp + 2048);
#pragma unroll
    for (int rt = 0; rt < RT; rt++) {
      bf16x8 a = ok[rt] ? *(const bf16x8*)(ar[rt] + kc * 32) : zz;
      acc[rt][0] = __builtin_amdgcn_mfma_f32_16x16x32_bf16(a, b0, acc[rt][0], 0, 0, 0);
      acc[rt][1] = __builtin_amdgcn_mfma_f32_16x16x32_bf16(a, b1, acc[rt][1], 0, 0, 0);
      acc[rt][2] = __builtin_amdgcn_mfma_f32_16x16x32_bf16(a, b2, acc[rt][2], 0, 0, 0);
      acc[rt][3] = __builtin_amdgcn_mfma_f32_16x16x32_bf16(a, b3, acc[rt][3], 0, 0, 0);
      acc[rt][4] = __builtin_amdgcn_mfma_f32_16x16x32_bf16(a, b4, acc[rt][4], 0, 0, 0);
    }
  }
  int col = grp * 16 + m;
  float b0 = bias5[col], b1 = bias5[256 + col], b2 = bias5[512 + col];
  float b3 = bias5[768 + col], b4 = bias5[1024 + col];
#pragma unroll
  for (int rt = 0; rt < RT; rt++) {
#pragma unroll
    for (int reg = 0; reg < 4; reg++) {
      int row = (tb + rt) * 16 + quad * 4 + reg;
      if (row >= B) continue;
      float u = tanhf(acc[rt][0][reg] + b0);
      float ig = sigf(acc[rt][1][reg] + b1);
      float lf = sigf(acc[rt][2][reg] + b2);
      float rf = sigf(acc[rt][3][reg] + b3);
      float o = sigf(acc[rt][4][reg] + b4);
      float lc = cprev[(2 * row) * MEM + col];
      float rc = cprev[(2 * row + 1) * MEM + col];
      float c = ig * u + lf * lc + rf * rc;
      cO[row * MEM + col] = c;
      hO[row * MEM + col] = f2b(o * tanhf(c));
    }
  }
}

// ---- Cooperative fused tail: levels B=128..1, 16 blocks x 256 threads ----
// Block = one column group g; its Wcf slice (16kc x 5 gates x 1KB = 80KB)
// staged in LDS once and reused across all 8 levels. grid.sync() per level.
// Ping-pong through global cP0/cP1 (each level fully consumes its input
// before the sync, so buffer reuse is hazard-free).
__global__ __launch_bounds__(256) void k_tail(
    const float* __restrict__ cs0, const unsigned short* __restrict__ hs0,
    float* __restrict__ cP0, unsigned short* __restrict__ hP0,
    float* __restrict__ cP1, unsigned short* __restrict__ hP1,
    const unsigned short* __restrict__ Wcf, const float* __restrict__ bias5,
    float* __restrict__ outv) {
  cg::grid_group grid = cg::this_grid();
  __shared__ unsigned short wl[40960];  // 80KB: [kc*5+gate][512]
  int g = blockIdx.x;                   // 0..15 column group
  int tid = threadIdx.x;

  // Stage this grp's weight slice: frag i=kc*5+gate <- Wcf frag (kc*16+g)*5+gate
#pragma unroll
  for (int j = 0; j < 20; j++) {
    int off8 = (j * 256 + tid) * 8;  // ushort index, 16B granule
    int i = off8 >> 9;               // frag 0..79
    int inner = off8 & 511;
    int kc = i / 5, gate = i - kc * 5;
    *(bf16x8*)&wl[off8] =
        *(const bf16x8*)(Wcf + (((kc * 16 + g) * 5 + gate) << 9) + inner);
  }
  __syncthreads();

  int lane = tid & 63, wave = tid >> 6;
  int m = lane & 15, quad = lane >> 4;
  int col = g * 16 + m;
  float bb0 = bias5[col], bb1 = bias5[256 + col], bb2 = bias5[512 + col];
  float bb3 = bias5[768 + col], bb4 = bias5[1024 + col];
  const bf16x8 zz = {0, 0, 0, 0, 0, 0, 0, 0};

  const float* cs = cs0;
  const unsigned short* hs = hs0;
  int B = 128, par = 0;
  while (B >= 1) {
    float* dc = par ? cP1 : cP0;
    unsigned short* dh = par ? hP1 : hP0;
    int tiles = (B + 15) >> 4;
    // wave handles tiles (wave) and (wave+4); B-frags shared across both
    int t0 = wave, t1 = wave + 4;
    bool u1 = (t1 < tiles);

    auto store_tile = [&](const f32x4* a, int t) {
#pragma unroll
      for (int reg = 0; reg < 4; reg++) {
        int row = t * 16 + quad * 4 + reg;
        if (row >= B) continue;
        float u = tanhf(a[0][reg] + bb0);
        float ig = sigf(a[1][reg] + bb1);
        float lf = sigf(a[2][reg] + bb2);
        float rf = sigf(a[3][reg] + bb3);
        float o = sigf(a[4][reg] + bb4);
        float lc = cs[(2 * row) * MEM + col];
        float rc = cs[(2 * row + 1) * MEM + col];
        float c = ig * u + lf * lc + rf * rc;
        float h = o * tanhf(c);
        if (B == 1) {
          outv[col] = c;
          outv[256 + col] = h;
        } else {
          dc[row * MEM + col] = c;
          dh[row * MEM + col] = f2b(h);
        }
      }
    };

    if (t0 < tiles) {
      f32x4 a0[5], a1[5];
#pragma unroll
      for (int q = 0; q < 5; q++) {
        a0[q] = (f32x4){0.f, 0.f, 0.f, 0.f};
        a1[q] = (f32x4){0.f, 0.f, 0.f, 0.f};
      }
      int ra0 = t0 * 16 + m, ra1 = t1 * 16 + m;
      bool ok0 = (ra0 < B), ok1 = u1 && (ra1 < B);
      const unsigned short* ar0 = hs + ra0 * 512 + quad * 8;
      const unsigned short* ar1 = hs + ra1 * 512 + quad * 8;
#pragma unroll
      for (int kc = 0; kc < 16; kc++) {
        bf16x8 w0 = *(const bf16x8*)&wl[(kc * 5 + 0) * 512 + lane * 8];
        bf16x8 w1 = *(const bf16x8*)&wl[(kc * 5 + 1) * 512 + lane * 8];
        bf16x8 w2 = *(const bf16x8*)&wl[(kc * 5 + 2) * 512 + lane * 8];
        bf16x8 w3 = *(const bf16x8*)&wl[(kc * 5 + 3) * 512 + lane * 8];
        bf16x8 w4 = *(const bf16x8*)&wl[(kc * 5 + 4) * 512 + lane * 8];
        bf16x8 av0 = ok0 ? *(const bf16x8*)(ar0 + kc * 32) : zz;
        a0[0] = __builtin_amdgcn_mfma_f32_16x16x32_bf16(av0, w0, a0[0], 0, 0, 0);
        a0[1] = __builtin_amdgcn_mfma_f32_16x16x32_bf16(av0, w1, a0[1], 0, 0, 0);
        a0[2] = __builtin_amdgcn_mfma_f32_16x16x32_bf16(av0, w2, a0[2], 0, 0, 0);
        a0[3] = __builtin_amdgcn_mfma_f32_16x16x32_bf16(av0, w3, a0[3], 0, 0, 0);
        a0[4] = __builtin_amdgcn_mfma_f32_16x16x32_bf16(av0, w4, a0[4], 0, 0, 0);
        if (u1) {
          bf16x8 av1 = ok1 ? *(const bf16x8*)(ar1 + kc * 32) : zz;
          a1[0] = __builtin_amdgcn_mfma_f32_16x16x32_bf16(av1, w0, a1[0], 0, 0, 0);
          a1[1] = __builtin_amdgcn_mfma_f32_16x16x32_bf16(av1, w1, a1[1], 0, 0, 0);
          a1[2] = __builtin_amdgcn_mfma_f32_16x16x32_bf16(av1, w2, a1[2], 0, 0, 0);
          a1[3] = __builtin_amdgcn_mfma_f32_16x16x32_bf16(av1, w3, a1[3], 0, 0, 0);
          a1[4] = __builtin_amdgcn_mfma_f32_16x16x32_bf16(av1, w4, a1[4], 0, 0, 0);
        }
      }
      store_tile(a0, t0);
      if (u1) store_tile(a1, t1);
    }
    if (B == 1) break;  // uniform across grid
    grid.sync();
    cs = dc;
    hs = dh;
    par ^= 1;
    B >>= 1;
  }
}

extern "C" void kernel_launch(void* const* d_in, const int* in_sizes, int n_in,
                              void* d_out, int out_size, void* d_ws, size_t ws_size,
                              hipStream_t stream) {
  const float* embs = (const float*)d_in[0];
  const float* Wx = (const float*)d_in[1];
  const float* bx = (const float*)d_in[2];
  const float* Wl = (const float*)d_in[3];
  const float* Wr = (const float*)d_in[4];
  const float* emb_table = (const float*)d_in[5];
  float* out = (float*)d_out;

  // Workspace layout, ~24.7 MB
  float* ws = (float*)d_ws;
  float* cA = ws;                               // 8192*256 f32
  float* cB = cA + 8192 * 256;                  // 4096*256 f32
  float* bias5 = cB + 4096 * 256;               // 1280 f32
  unsigned short* hA = (unsigned short*)(bias5 + 1280);  // 8192*256 bf16
  unsigned short* hB = hA + 8192 * 256;                  // 4096*256 bf16
  unsigned short* Wcf = hB + 4096 * 256;                 // 1280*512
  unsigned short* Wxf = Wcf + 1280 * 512;                // 480*512
  unsigned short* eb = Wxf + 480 * 512;                  // 8192*320

  // Fused one-time prep (13765 blocks)
  k_prep<<<NB_WCF + NB_WXF + NB_EB + 5, 256, 0, stream>>>(
      Wl, Wr, Wx, bx, embs, emb_table + (in_sizes[5] - 300),
      Wcf, Wxf, eb, bias5);

  // Leaf level -> cA (f32), hA (bf16); RT=2
  k_leaf_mfma<<<dim3(64, 16), 256, 0, stream>>>(eb, Wxf, bx, cA, hA);

  // Regular tree levels B=4096..256 (5 launches)
  const float* cs = cA;
  const unsigned short* hs = hA;
  int B = 4096;
  int lvl = 0;
  while (B >= 256) {
    float* dc;
    unsigned short* dh;
    if ((lvl & 1) == 0) { dc = cB; dh = hB; } else { dc = cA; dh = hA; }
    int tiles = B >> 4;
    if (B == 4096) {
      k_compose_mfma<2><<<dim3(tiles / 8, 16), 256, 0, stream>>>(
          hs, cs, Wcf, bias5, dc, dh, B);
    } else {
      k_compose_mfma<1><<<dim3(tiles / 4, 16), 256, 0, stream>>>(
          hs, cs, Wcf, bias5, dc, dh, B);
    }
    cs = dc;
    hs = dh;
    B >>= 1;
    lvl++;
  }
  // After loop: B=256-level output lives in cB/hB (lvl4 even). Tail: B=128..1.
  const float* cs0 = cs;                 // = cB
  const unsigned short* hs0 = hs;        // = hB
  float* cP0 = cA; unsigned short* hP0 = hA;
  float* cP1 = cB; unsigned short* hP1 = hB;
  const unsigned short* Wcf_c = Wcf;
  const float* bias5_c = bias5;
  float* out_p = out;
  void* args[] = {(void*)&cs0, (void*)&hs0, (void*)&cP0, (void*)&hP0,
                  (void*)&cP1, (void*)&hP1, (void*)&Wcf_c, (void*)&bias5_c,
                  (void*)&out_p};
  hipLaunchCooperativeKernel((void*)k_tail, dim3(16), dim3(256), args, 0, stream);
}

// Round 2
// 260.940 us; speedup vs baseline: 1.1932x; 1.1932x over previous
//
#include <hip/hip_runtime.h>
#include <math.h>

// BinaryTreeLSTM on MI355X — R5.
// vs R4 (311us): REVERT cooperative tail (grid.sync measured ~9us each ->
// 82.8us kernel; launches are cheaper). Back to per-level launches for all
// 13 tree levels. KEEP RT=2 (two row-tiles per wave sharing B-frags) for
// leaf and B=4096 compose.
// Dispatches: prep, leaf, compose x13 = 15.

#define MEM 256

typedef __attribute__((ext_vector_type(8))) short bf16x8;
typedef __attribute__((ext_vector_type(4))) float f32x4;

__device__ __forceinline__ float sigf(float x) { return 1.0f / (1.0f + __expf(-x)); }

__device__ __forceinline__ unsigned short f2b(float f) {
  unsigned int u = __float_as_uint(f);
  u = (u + 0x7FFFu + ((u >> 16) & 1u)) >> 16;
  return (unsigned short)u;
}

// ---- Fused one-time prep: Wcf shuffle | Wxf shuffle | embs->bf16 | bias5 ----
#define NB_WCF 2560
#define NB_WXF 960
#define NB_EB 10240
__global__ __launch_bounds__(256) void k_prep(
    const float* __restrict__ Wl, const float* __restrict__ Wr,
    const float* __restrict__ Wx, const float* __restrict__ bx,
    const float* __restrict__ embs, const float* __restrict__ emb_last,
    unsigned short* __restrict__ Wcf, unsigned short* __restrict__ Wxf,
    unsigned short* __restrict__ eb, float* __restrict__ bias5) {
  int b = blockIdx.x;
  if (b < NB_WCF) {
    int idx = b * 256 + threadIdx.x;  // 1280*512
    int f = idx >> 9, r = idx & 511;
    int lane = r >> 3, j = r & 7;
    int gate = f % 5, t = f / 5;
    int grp = t & 15, kc = t >> 4;
    int k = kc * 32 + ((lane >> 4) << 3) + j;
    int n = gate * 256 + (grp << 4) + (lane & 15);
    float v = (k < 256) ? Wl[n * 256 + k] : Wr[n * 256 + (k - 256)];
    Wcf[idx] = f2b(v);
  } else if (b < NB_WCF + NB_WXF) {
    int idx = (b - NB_WCF) * 256 + threadIdx.x;  // 480*512
    int f = idx >> 9, r = idx & 511;
    int lane = r >> 3, j = r & 7;
    int gate = f % 3, t = f / 3;
    int grp = t & 15, kc = t >> 4;
    int k = kc * 32 + ((lane >> 4) << 3) + j;
    const int gmap[3] = {0, 1, 3};
    int n = gmap[gate] * 256 + (grp << 4) + (lane & 15);
    float v = (k < 300) ? Wx[n * 300 + k] : 0.0f;
    Wxf[idx] = f2b(v);
  } else if (b < NB_WCF + NB_WXF + NB_EB) {
    int idx = (b - NB_WCF - NB_WXF) * 256 + threadIdx.x;  // 8192*320
    int row = idx / 320;
    int k = idx - row * 320;
    eb[idx] = (k < 300) ? f2b(embs[row * 300 + k]) : (unsigned short)0;
  } else {
    int g = b - (NB_WCF + NB_WXF + NB_EB);  // 0..4
    __shared__ float er[300];
    for (int k = threadIdx.x; k < 300; k += 256) er[k] = emb_last[k];
    __syncthreads();
    const int map[5] = {0, 1, 2, 2, 3};
    int wrow = map[g] * 256 + threadIdx.x;
    const float* w = Wx + wrow * 300;
    float s = bx[wrow];
    for (int k = 0; k < 300; k++) s += er[k] * w[k];
    bias5[g * 256 + threadIdx.x] = s;
  }
}

// ---- Leaf: grid(64,16); wave = 2 row tiles, grp=blockIdx.y ----
__global__ __launch_bounds__(256) void k_leaf_mfma(
    const unsigned short* __restrict__ eb, const unsigned short* __restrict__ Wxf,
    const float* __restrict__ bx, float* __restrict__ cO,
    unsigned short* __restrict__ hO) {
  int lane = threadIdx.x & 63;
  int wave = threadIdx.x >> 6;
  int grp = blockIdx.y;                     // 0..15 column group
  int tb = (blockIdx.x * 4 + wave) * 2;     // 0..510 row tile base
  int m = lane & 15, quad = lane >> 4;

  f32x4 acc[2][3];
#pragma unroll
  for (int rt = 0; rt < 2; rt++)
#pragma unroll
    for (int g = 0; g < 3; g++) acc[rt][g] = (f32x4){0.f, 0.f, 0.f, 0.f};

  const unsigned short* ar0 = eb + (tb * 16 + m) * 320 + quad * 8;
  const unsigned short* ar1 = eb + ((tb + 1) * 16 + m) * 320 + quad * 8;
#pragma unroll
  for (int kc = 0; kc < 10; kc++) {
    const unsigned short* bp = Wxf + ((kc * 16 + grp) * 3) * 512 + lane * 8;
    bf16x8 b0 = *(const bf16x8*)(bp);
    bf16x8 b1 = *(const bf16x8*)(bp + 512);
    bf16x8 b2 = *(const bf16x8*)(bp + 1024);
    bf16x8 a0 = *(const bf16x8*)(ar0 + kc * 32);
    bf16x8 a1 = *(const bf16x8*)(ar1 + kc * 32);
    acc[0][0] = __builtin_amdgcn_mfma_f32_16x16x32_bf16(a0, b0, acc[0][0], 0, 0, 0);
    acc[0][1] = __builtin_amdgcn_mfma_f32_16x16x32_bf16(a0, b1, acc[0][1], 0, 0, 0);
    acc[0][2] = __builtin_amdgcn_mfma_f32_16x16x32_bf16(a0, b2, acc[0][2], 0, 0, 0);
    acc[1][0] = __builtin_amdgcn_mfma_f32_16x16x32_bf16(a1, b0, acc[1][0], 0, 0, 0);
    acc[1][1] = __builtin_amdgcn_mfma_f32_16x16x32_bf16(a1, b1, acc[1][1], 0, 0, 0);
    acc[1][2] = __builtin_amdgcn_mfma_f32_16x16x32_bf16(a1, b2, acc[1][2], 0, 0, 0);
  }
  int col = grp * 16 + m;
  float b0 = bx[col], b1 = bx[256 + col], b3 = bx[768 + col];
#pragma unroll
  for (int rt = 0; rt < 2; rt++) {
#pragma unroll
    for (int reg = 0; reg < 4; reg++) {
      int row = (tb + rt) * 16 + quad * 4 + reg;
      float u = tanhf(acc[rt][0][reg] + b0);
      float ig = sigf(acc[rt][1][reg] + b1);
      float o = sigf(acc[rt][2][reg] + b3);
      float c = ig * u;
      cO[row * MEM + col] = c;
      hO[row * MEM + col] = f2b(o * tanhf(c));
    }
  }
}

// ---- Compose: template RT row-tiles per wave; grid(ceil(tiles/(4*RT)),16) ----
template <int RT>
__global__ __launch_bounds__(256) void k_compose_mfma(
    const unsigned short* __restrict__ hprev,  // B x 512 bf16 (view)
    const float* __restrict__ cprev,           // 2B x 256 fp32
    const unsigned short* __restrict__ Wcf, const float* __restrict__ bias5,
    float* __restrict__ cO, unsigned short* __restrict__ hO,
    float* __restrict__ hOf,  // non-null on final level: fp32 h out
    int B) {
  int lane = threadIdx.x & 63;
  int wave = threadIdx.x >> 6;
  int grp = blockIdx.y;                       // 0..15
  int tb = (blockIdx.x * 4 + wave) * RT;      // row tile base
  if (tb * 16 >= B) return;                   // idle wave (no barriers below)
  int m = lane & 15, quad = lane >> 4;
  const bf16x8 zz = {0, 0, 0, 0, 0, 0, 0, 0};

  f32x4 acc[RT][5];
  const unsigned short* ar[RT];
  bool ok[RT];
#pragma unroll
  for (int rt = 0; rt < RT; rt++) {
    int ra = (tb + rt) * 16 + m;
    ok[rt] = (ra < B);
    ar[rt] = hprev + ra * 512 + quad * 8;
#pragma unroll
    for (int g = 0; g < 5; g++) acc[rt][g] = (f32x4){0.f, 0.f, 0.f, 0.f};
  }

#pragma unroll
  for (int kc = 0; kc < 16; kc++) {
    const unsigned short* bp = Wcf + ((kc * 16 + grp) * 5) * 512 + lane * 8;
    bf16x8 b0 = *(const bf16x8*)(bp);
    bf16x8 b1 = *(const bf16x8*)(bp + 512);
    bf16x8 b2 = *(const bf16x8*)(bp + 1024);
    bf16x8 b3 = *(const bf16x8*)(bp + 1536);
    bf16x8 b4 = *(const bf16x8*)(bp + 2048);
#pragma unroll
    for (int rt = 0; rt < RT; rt++) {
      bf16x8 a = ok[rt] ? *(const bf16x8*)(ar[rt] + kc * 32) : zz;
      acc[rt][0] = __builtin_amdgcn_mfma_f32_16x16x32_bf16(a, b0, acc[rt][0], 0, 0, 0);
      acc[rt][1] = __builtin_amdgcn_mfma_f32_16x16x32_bf16(a, b1, acc[rt][1], 0, 0, 0);
      acc[rt][2] = __builtin_amdgcn_mfma_f32_16x16x32_bf16(a, b2, acc[rt][2], 0, 0, 0);
      acc[rt][3] = __builtin_amdgcn_mfma_f32_16x16x32_bf16(a, b3, acc[rt][3], 0, 0, 0);
      acc[rt][4] = __builtin_amdgcn_mfma_f32_16x16x32_bf16(a, b4, acc[rt][4], 0, 0, 0);
    }
  }
  int col = grp * 16 + m;
  float b0 = bias5[col], b1 = bias5[256 + col], b2 = bias5[512 + col];
  float b3 = bias5[768 + col], b4 = bias5[1024 + col];
#pragma unroll
  for (int rt = 0; rt < RT; rt++) {
#pragma unroll
    for (int reg = 0; reg < 4; reg++) {
      int row = (tb + rt) * 16 + quad * 4 + reg;
      if (row >= B) continue;
      float u = tanhf(acc[rt][0][reg] + b0);
      float ig = sigf(acc[rt][1][reg] + b1);
      float lf = sigf(acc[rt][2][reg] + b2);
      float rf = sigf(acc[rt][3][reg] + b3);
      float o = sigf(acc[rt][4][reg] + b4);
      float lc = cprev[(2 * row) * MEM + col];
      float rc = cprev[(2 * row + 1) * MEM + col];
      float c = ig * u + lf * lc + rf * rc;
      float h = o * tanhf(c);
      cO[row * MEM + col] = c;
      hO[row * MEM + col] = f2b(h);
      if (hOf) hOf[row * MEM + col] = h;
    }
  }
}

extern "C" void kernel_launch(void* const* d_in, const int* in_sizes, int n_in,
                              void* d_out, int out_size, void* d_ws, size_t ws_size,
                              hipStream_t stream) {
  const float* embs = (const float*)d_in[0];
  const float* Wx = (const float*)d_in[1];
  const float* bx = (const float*)d_in[2];
  const float* Wl = (const float*)d_in[3];
  const float* Wr = (const float*)d_in[4];
  const float* emb_table = (const float*)d_in[5];
  float* out = (float*)d_out;

  // Workspace layout, ~24.7 MB
  float* ws = (float*)d_ws;
  float* cA = ws;                               // 8192*256 f32
  float* cB = cA + 8192 * 256;                  // 4096*256 f32
  float* bias5 = cB + 4096 * 256;               // 1280 f32
  unsigned short* hA = (unsigned short*)(bias5 + 1280);  // 8192*256 bf16
  unsigned short* hB = hA + 8192 * 256;                  // 4096*256 bf16
  unsigned short* Wcf = hB + 4096 * 256;                 // 1280*512
  unsigned short* Wxf = Wcf + 1280 * 512;                // 480*512
  unsigned short* eb = Wxf + 480 * 512;                  // 8192*320

  // Fused one-time prep (13765 blocks)
  k_prep<<<NB_WCF + NB_WXF + NB_EB + 5, 256, 0, stream>>>(
      Wl, Wr, Wx, bx, embs, emb_table + (in_sizes[5] - 300),
      Wcf, Wxf, eb, bias5);

  // Leaf level -> cA (f32), hA (bf16); RT=2
  k_leaf_mfma<<<dim3(64, 16), 256, 0, stream>>>(eb, Wxf, bx, cA, hA);

  // 13 tree levels, per-level launches
  const float* cs = cA;
  const unsigned short* hs = hA;
  int B = 4096;
  int lvl = 0;
  while (B >= 1) {
    float* dc;
    unsigned short* dh;
    float* dhf = nullptr;
    if (B == 1) {
      dc = out;
      dh = hB;  // dummy bf16 sink
      dhf = out + 256;
    } else if ((lvl & 1) == 0) {
      dc = cB; dh = hB;
    } else {
      dc = cA; dh = hA;
    }
    int tiles = (B + 15) / 16;
    if (B == 4096) {
      k_compose_mfma<2><<<dim3(tiles / 8, 16), 256, 0, stream>>>(
          hs, cs, Wcf, bias5, dc, dh, dhf, B);
    } else {
      int gx = (tiles + 3) / 4;
      k_compose_mfma<1><<<dim3(gx, 16), 256, 0, stream>>>(
          hs, cs, Wcf, bias5, dc, dh, dhf, B);
    }
    cs = dc;
    hs = dh;
    B >>= 1;
    lvl++;
  }
}